// Round 10
// baseline (159.534 us; speedup 1.0000x reference)
//
#include <hip/hip_runtime.h>
#include <stdint.h>

#define MARGIN 0.3f
#define EPS 1e-12f

typedef __attribute__((ext_vector_type(8))) __bf16 bf16x8;
typedef __attribute__((ext_vector_type(4))) float f32x4;

// round-to-nearest-even fp32 -> bf16
__device__ __forceinline__ unsigned short f2bf(float f) {
    unsigned u = __float_as_uint(f);
    unsigned r = (u + 0x7FFFu + ((u >> 16) & 1u)) >> 16;
    return (unsigned short)r;
}

#define GLD16(gp, lp)                                                     \
    __builtin_amdgcn_global_load_lds(                                     \
        (const __attribute__((address_space(1))) void*)(gp),              \
        (__attribute__((address_space(3))) void*)(lp), 16, 0, 0)

// ---------------------------------------------------------------------------
// Kernel 1: fp32 -> bf16 convert, fp32 row norms, init ap/an/ctr.
// One WAVE per row. grid = n/4 blocks of 256.
// ---------------------------------------------------------------------------
__global__ __launch_bounds__(256) void prep_kernel(
    const float* __restrict__ X, unsigned short* __restrict__ Xbf,
    float* __restrict__ sqg, unsigned* __restrict__ apb,
    unsigned* __restrict__ anb, unsigned* __restrict__ ctr, int d) {
    const int wave = threadIdx.x >> 6, lane = threadIdx.x & 63;
    const int row = blockIdx.x * 4 + wave;
    const float4* Xr = (const float4*)(X + (size_t)row * d);
    ushort4* Or = (ushort4*)(Xbf + (size_t)row * d);
    float s = 0.0f;
    const int nq = d >> 2;
    for (int i = lane; i < nq; i += 64) {
        float4 v = Xr[i];
        s += v.x * v.x + v.y * v.y + v.z * v.z + v.w * v.w;
        ushort4 o;
        o.x = f2bf(v.x); o.y = f2bf(v.y); o.z = f2bf(v.z); o.w = f2bf(v.w);
        Or[i] = o;
    }
    for (int off = 32; off > 0; off >>= 1) s += __shfl_down(s, off, 64);
    if (lane == 0) {
        sqg[row] = s;
        apb[row] = 0u;            // dist >= 0: uint compare == float compare
        anb[row] = 0x7F800000u;   // +inf
    }
    if (blockIdx.x == 0 && threadIdx.x == 0) ctr[0] = 0u;
}

// ---------------------------------------------------------------------------
// Kernel 2: 256x256-tile full-square Gram + distance + row-side hard mining.
// Catalog 2-phase template (m230-V0, 682 TF refcheck'd): 8 waves (2M x 4N),
// per-wave 128x64 output = acc[8][4], BK=64 (2 MFMA k-halves), 128 KB LDS
// double-buffered, STAGE(next) -> compute(cur) -> one __syncthreads per step.
// Full square grid (16x16 = 256 blocks = 1/CU): every ordered pair computed,
// so only the verified row-side mining epilogue is needed.
// Last block (atomic counter) computes the final loss/precision.
// ---------------------------------------------------------------------------
#define BM 256
#define BN 256
#define BK 64

__global__ __launch_bounds__(512, 2) void gram_gemm(
    const unsigned short* __restrict__ Xbf, const float* __restrict__ sqg,
    const int* __restrict__ tgt, unsigned* __restrict__ apb,
    unsigned* __restrict__ anb, unsigned* __restrict__ ctr,
    float* __restrict__ out, int n, int d, int nblk) {
    __shared__ unsigned short ldsA[2][BM * BK];   // 2 x 32 KB
    __shared__ unsigned short ldsB[2][BN * BK];   // 2 x 32 KB

    const int tid  = threadIdx.x;
    const int lane = tid & 63;
    const int wave = tid >> 6;          // 0..7
    const int wm = wave >> 2;           // 0..1 (row group of 128)
    const int wn = wave & 3;            // 0..3 (col group of 64)
    const int lo = lane & 15, hi = lane >> 4;

    // XCD swizzle: 256 blocks -> xcd gets 32 consecutive bids (2 A-panels)
    const int orig = blockIdx.x;
    const int bid = (orig & 7) * 32 + (orig >> 3);
    const int bi = bid >> 4, bj = bid & 15;
    const int rowBase = bi * BM;
    const int colBase = bj * BN;

    // staging: chunk = 8 rows x 128 B = 1 KB. A/B each 32 chunks; wave w
    // stages chunks w*4..w*4+3 of each. lane -> (row lane>>3, k (lane&7)*8).
    const int srow = lane >> 3;
    const int sk   = (lane & 7) * 8;
    const unsigned short* gA[4];
    const unsigned short* gB[4];
#pragma unroll
    for (int c = 0; c < 4; ++c) {
        const int rr = wave * 32 + c * 8 + srow;
        gA[c] = Xbf + (size_t)(rowBase + rr) * d + sk;
        gB[c] = Xbf + (size_t)(colBase + rr) * d + sk;
    }

#define STAGE(bufi, k0)                                                   \
    do {                                                                  \
        _Pragma("unroll")                                                 \
        for (int c = 0; c < 4; ++c) {                                     \
            GLD16(gA[c] + (k0), &ldsA[bufi][(wave * 32 + c * 8) * BK]);   \
            GLD16(gB[c] + (k0), &ldsB[bufi][(wave * 32 + c * 8) * BK]);   \
        }                                                                 \
    } while (0)

    f32x4 acc[8][4] = {};

    const int nt = d / BK;              // 16
    int cur = 0;
    STAGE(0, 0);
    __syncthreads();                    // drains vmcnt; tile 0 ready

    for (int t = 0; t < nt; ++t) {
        if (t + 1 < nt) STAGE(cur ^ 1, (t + 1) * BK);
#pragma unroll
        for (int kk = 0; kk < 2; ++kk) {
            bf16x8 a[8], b[4];
#pragma unroll
            for (int mi = 0; mi < 8; ++mi)
                a[mi] = *(const bf16x8*)
                    &ldsA[cur][(wm * 128 + mi * 16 + lo) * BK + kk * 32 + hi * 8];
#pragma unroll
            for (int ni = 0; ni < 4; ++ni)
                b[ni] = *(const bf16x8*)
                    &ldsB[cur][(wn * 64 + ni * 16 + lo) * BK + kk * 32 + hi * 8];
#pragma unroll
            for (int mi = 0; mi < 8; ++mi)
#pragma unroll
                for (int ni = 0; ni < 4; ++ni)
                    acc[mi][ni] = __builtin_amdgcn_mfma_f32_16x16x32_bf16(
                        a[mi], b[ni], acc[mi][ni], 0, 0, 0);
        }
        __syncthreads();                // stage landed (vmcnt0) + all reads done
        cur ^= 1;
    }

    // ---------------- epilogue (row-side mining; verified mapping) ---------
    float sqj[4];
    int   tj[4];
#pragma unroll
    for (int ni = 0; ni < 4; ++ni) {
        const int gj = colBase + wn * 64 + ni * 16 + lo;
        sqj[ni] = sqg[gj];
        tj[ni]  = tgt[gj];
    }
#pragma unroll
    for (int mi = 0; mi < 8; ++mi) {
#pragma unroll
        for (int j = 0; j < 4; ++j) {
            const int gi = rowBase + wm * 128 + mi * 16 + hi * 4 + j;
            const float sqi = sqg[gi];
            const int   ti  = tgt[gi];
            float ap = 0.0f;
            float an = __uint_as_float(0x7F800000u);
#pragma unroll
            for (int ni = 0; ni < 4; ++ni) {
                const float d2 = sqi + sqj[ni] - 2.0f * acc[mi][ni][j];
                const float dist = sqrtf(fmaxf(d2, EPS));
                if (ti == tj[ni]) ap = fmaxf(ap, dist);
                else              an = fminf(an, dist);
            }
            // reduce across the 16 lanes (lo) holding this row
#pragma unroll
            for (int m = 1; m < 16; m <<= 1) {
                ap = fmaxf(ap, __shfl_xor(ap, m, 64));
                an = fminf(an, __shfl_xor(an, m, 64));
            }
            if (lo == 0) {
                atomicMax(&apb[gi], __float_as_uint(ap));
                atomicMin(&anb[gi], __float_as_uint(an));
            }
        }
    }

    // ---------------- last-block finalize ----------------
    __threadfence();
    __syncthreads();
    __shared__ int lastFlag;
    if (tid == 0) {
        unsigned prev = __hip_atomic_fetch_add(ctr, 1u, __ATOMIC_ACQ_REL,
                                               __HIP_MEMORY_SCOPE_AGENT);
        lastFlag = (prev == (unsigned)(nblk - 1)) ? 1 : 0;
    }
    __syncthreads();
    if (lastFlag) {
        float ls = 0.0f, pc = 0.0f;
        for (int i = tid; i < n; i += 512) {
            const float ap = __uint_as_float(__hip_atomic_load(
                &apb[i], __ATOMIC_RELAXED, __HIP_MEMORY_SCOPE_AGENT));
            const float an = __uint_as_float(__hip_atomic_load(
                &anb[i], __ATOMIC_RELAXED, __HIP_MEMORY_SCOPE_AGENT));
            ls += fmaxf(MARGIN - (an - ap), 0.0f);
            pc += (an > ap) ? 1.0f : 0.0f;
        }
        __shared__ float rl[8], rp[8];
        for (int off = 32; off > 0; off >>= 1) {
            ls += __shfl_down(ls, off, 64);
            pc += __shfl_down(pc, off, 64);
        }
        if ((tid & 63) == 0) { rl[tid >> 6] = ls; rp[tid >> 6] = pc; }
        __syncthreads();
        if (tid == 0) {
            float L = 0.0f, P = 0.0f;
#pragma unroll
            for (int w = 0; w < 8; ++w) { L += rl[w]; P += rp[w]; }
            out[0] = L / (float)n;
            out[1] = P / (float)n;
        }
    }
}

// ---------------------------------------------------------------------------
// Fallback path (only if shape/ws unsupported): pure fp32, zero workspace.
// ---------------------------------------------------------------------------
__global__ __launch_bounds__(256) void fb_zero(float* __restrict__ out) {
    if (threadIdx.x == 0) { out[0] = 0.0f; out[1] = 0.0f; }
}

__global__ __launch_bounds__(256) void fb_row(
    const float* __restrict__ X, const int* __restrict__ tgt,
    float* __restrict__ out, int n, int d) {
    __shared__ float xi[4096];  // supports d <= 4096
    const int i = blockIdx.x;
    const int tid = threadIdx.x;
    for (int k = tid; k < d; k += 256) xi[k] = X[(size_t)i * d + k];
    __syncthreads();
    const int ti = tgt[i];
    float ap = 0.0f;
    float an = __uint_as_float(0x7F800000u);
    for (int j = tid; j < n; j += 256) {
        const float4* Xj = (const float4*)(X + (size_t)j * d);
        float s = 0.0f;
        for (int k4 = 0; k4 < (d >> 2); ++k4) {
            float4 v = Xj[k4];
            float4 u = *(const float4*)&xi[k4 * 4];
            float dx = u.x - v.x, dy = u.y - v.y, dz = u.z - v.z, dw = u.w - v.w;
            s += dx * dx + dy * dy + dz * dz + dw * dw;
        }
        const float dist = sqrtf(fmaxf(s, EPS));
        if (tgt[j] == ti) ap = fmaxf(ap, dist);
        else              an = fminf(an, dist);
    }
    for (int m = 1; m < 64; m <<= 1) {
        ap = fmaxf(ap, __shfl_xor(ap, m, 64));
        an = fminf(an, __shfl_xor(an, m, 64));
    }
    __shared__ float rap[4], ran[4];
    const int wave = tid >> 6, lane = tid & 63;
    if (lane == 0) { rap[wave] = ap; ran[wave] = an; }
    __syncthreads();
    if (tid == 0) {
        ap = fmaxf(fmaxf(rap[0], rap[1]), fmaxf(rap[2], rap[3]));
        an = fminf(fminf(ran[0], ran[1]), fminf(ran[2], ran[3]));
        atomicAdd(&out[0], fmaxf(MARGIN - (an - ap), 0.0f));
        atomicAdd(&out[1], (an > ap) ? 1.0f : 0.0f);
    }
}

__global__ __launch_bounds__(64) void fb_scale(float* __restrict__ out, float inv_n) {
    if (threadIdx.x == 0) { out[0] *= inv_n; out[1] *= inv_n; }
}

// ---------------------------------------------------------------------------
extern "C" void kernel_launch(void* const* d_in, const int* in_sizes, int n_in,
                              void* d_out, int out_size, void* d_ws, size_t ws_size,
                              hipStream_t stream) {
    const float* X   = (const float*)d_in[0];
    const int*   tgt = (const int*)d_in[1];
    const int n = in_sizes[1];
    const int d = in_sizes[0] / n;

    const size_t need = (size_t)n * d * 2 + (size_t)n * 4 * 3 + 4;
    if (ws_size >= need && (n % BM) == 0 && (d % BK) == 0 &&
        ((n / BM) % 8 == 0 || (n / BM) * (n / BM) % 8 == 0)) {
        char* ws = (char*)d_ws;
        unsigned short* Xbf = (unsigned short*)ws;                 // n*d*2 B
        float*    sqg = (float*)(ws + (size_t)n * d * 2);          // n*4 B
        unsigned* apb = (unsigned*)((char*)sqg + (size_t)n * 4);   // n*4 B
        unsigned* anb = apb + n;                                   // n*4 B
        unsigned* ctr = anb + n;                                   // 4 B

        const int nb = n / BM;                 // 16
        const int nblk = nb * nb;              // 256
        prep_kernel<<<n / 4, 256, 0, stream>>>(X, Xbf, sqg, apb, anb, ctr, d);
        gram_gemm<<<nblk, 512, 0, stream>>>(Xbf, sqg, tgt, apb, anb, ctr,
                                            (float*)d_out, n, d, nblk);
    } else {
        fb_zero<<<1, 256, 0, stream>>>((float*)d_out);
        fb_row<<<n, 256, 0, stream>>>(X, tgt, (float*)d_out, n, d);
        fb_scale<<<1, 64, 0, stream>>>((float*)d_out, 1.0f / (float)n);
    }
}

// Round 11
// 154.236 us; speedup vs baseline: 1.0344x; 1.0344x over previous
//
#include <hip/hip_runtime.h>
#include <stdint.h>

#define MARGIN 0.3f
#define EPS 1e-12f

typedef __attribute__((ext_vector_type(8))) __bf16 bf16x8;
typedef __attribute__((ext_vector_type(4))) float f32x4;

// round-to-nearest-even fp32 -> bf16
__device__ __forceinline__ unsigned short f2bf(float f) {
    unsigned u = __float_as_uint(f);
    unsigned r = (u + 0x7FFFu + ((u >> 16) & 1u)) >> 16;
    return (unsigned short)r;
}

#define GLD16(gp, lp)                                                     \
    __builtin_amdgcn_global_load_lds(                                     \
        (const __attribute__((address_space(1))) void*)(gp),              \
        (__attribute__((address_space(3))) void*)(lp), 16, 0, 0)

// ---------------------------------------------------------------------------
// Kernel 1: fp32 -> bf16 convert, fp32 row norms, init ap/an/ctr.
// One WAVE per row. grid = n/4 blocks of 256.
// ---------------------------------------------------------------------------
__global__ __launch_bounds__(256) void prep_kernel(
    const float* __restrict__ X, unsigned short* __restrict__ Xbf,
    float* __restrict__ sqg, unsigned* __restrict__ apb,
    unsigned* __restrict__ anb, unsigned* __restrict__ ctr, int d) {
    const int wave = threadIdx.x >> 6, lane = threadIdx.x & 63;
    const int row = blockIdx.x * 4 + wave;
    const float4* Xr = (const float4*)(X + (size_t)row * d);
    ushort4* Or = (ushort4*)(Xbf + (size_t)row * d);
    float s = 0.0f;
    const int nq = d >> 2;
    for (int i = lane; i < nq; i += 64) {
        float4 v = Xr[i];
        s += v.x * v.x + v.y * v.y + v.z * v.z + v.w * v.w;
        ushort4 o;
        o.x = f2bf(v.x); o.y = f2bf(v.y); o.z = f2bf(v.z); o.w = f2bf(v.w);
        Or[i] = o;
    }
    for (int off = 32; off > 0; off >>= 1) s += __shfl_down(s, off, 64);
    if (lane == 0) {
        sqg[row] = s;
        apb[row] = 0u;            // dist >= 0: uint compare == float compare
        anb[row] = 0x7F800000u;   // +inf
    }
    if (blockIdx.x == 0 && threadIdx.x == 0) ctr[0] = 0u;
}

// ---------------------------------------------------------------------------
// Kernel 2: 256x256-tile full-square Gram + distance + row-side hard mining.
// r10 structure + T2 XOR-swizzle + T5 setprio.
// Swizzle (rule #21, both-sides-or-neither): LDS dest stays LINEAR
// (global_load_lds requirement); the global SOURCE column slot is
// pre-permuted per-lane (slot ^= row&7 on the 16B slot index within each
// 128B row), and ds_read applies the same XOR. 16 lanes -> 8 distinct 16B
// slots spanning all 32 banks, 2-way aliasing (free, m136).
// ---------------------------------------------------------------------------
#define BM 256
#define BN 256
#define BK 64

__global__ __launch_bounds__(512, 2) void gram_gemm(
    const unsigned short* __restrict__ Xbf, const float* __restrict__ sqg,
    const int* __restrict__ tgt, unsigned* __restrict__ apb,
    unsigned* __restrict__ anb, unsigned* __restrict__ ctr,
    float* __restrict__ out, int n, int d, int nblk) {
    __shared__ unsigned short ldsA[2][BM * BK];   // 2 x 32 KB
    __shared__ unsigned short ldsB[2][BN * BK];   // 2 x 32 KB

    const int tid  = threadIdx.x;
    const int lane = tid & 63;
    const int wave = tid >> 6;          // 0..7
    const int wm = wave >> 2;           // 0..1 (row group of 128)
    const int wn = wave & 3;            // 0..3 (col group of 64)
    const int lo = lane & 15, hi = lane >> 4;

    // XCD swizzle: 256 blocks -> xcd gets 32 consecutive bids (2 A-panels)
    const int orig = blockIdx.x;
    const int bid = (orig & 7) * 32 + (orig >> 3);
    const int bi = bid >> 4, bj = bid & 15;
    const int rowBase = bi * BM;
    const int colBase = bj * BN;

    // staging: chunk = 8 rows x 128 B = 1 KB. A/B each 32 chunks; wave w
    // stages chunks w*4..w*4+3. lane -> row (lane>>3), 16B-slot (lane&7).
    // SOURCE pre-swizzle: load global slot ((lane&7) ^ srow) so that the
    // linear LDS write leaves the data at slot ^ (row&7).
    const int srow = lane >> 3;                       // 0..7 within chunk
    const int sk   = (((lane & 7) ^ srow) * 8);       // swizzled k-offset (elems)
    const unsigned short* gA[4];
    const unsigned short* gB[4];
#pragma unroll
    for (int c = 0; c < 4; ++c) {
        const int rr = wave * 32 + c * 8 + srow;
        gA[c] = Xbf + (size_t)(rowBase + rr) * d + sk;
        gB[c] = Xbf + (size_t)(colBase + rr) * d + sk;
    }

#define STAGE(bufi, k0)                                                   \
    do {                                                                  \
        _Pragma("unroll")                                                 \
        for (int c = 0; c < 4; ++c) {                                     \
            GLD16(gA[c] + (k0), &ldsA[bufi][(wave * 32 + c * 8) * BK]);   \
            GLD16(gB[c] + (k0), &ldsB[bufi][(wave * 32 + c * 8) * BK]);   \
        }                                                                 \
    } while (0)

    f32x4 acc[8][4] = {};

    const int nt = d / BK;              // 16
    int cur = 0;
    STAGE(0, 0);
    __syncthreads();                    // drains vmcnt; tile 0 ready

    for (int t = 0; t < nt; ++t) {
        if (t + 1 < nt) STAGE(cur ^ 1, (t + 1) * BK);
#pragma unroll
        for (int kk = 0; kk < 2; ++kk) {
            bf16x8 a[8], b[4];
            // swizzled read: slot = (kk*4 + hi) ^ (row&7), row&7 == lo&7
            const int slot = ((kk * 4 + hi) ^ (lo & 7)) * 8;
#pragma unroll
            for (int mi = 0; mi < 8; ++mi)
                a[mi] = *(const bf16x8*)
                    &ldsA[cur][(wm * 128 + mi * 16 + lo) * BK + slot];
#pragma unroll
            for (int ni = 0; ni < 4; ++ni)
                b[ni] = *(const bf16x8*)
                    &ldsB[cur][(wn * 64 + ni * 16 + lo) * BK + slot];
            __builtin_amdgcn_s_setprio(1);
#pragma unroll
            for (int mi = 0; mi < 8; ++mi)
#pragma unroll
                for (int ni = 0; ni < 4; ++ni)
                    acc[mi][ni] = __builtin_amdgcn_mfma_f32_16x16x32_bf16(
                        a[mi], b[ni], acc[mi][ni], 0, 0, 0);
            __builtin_amdgcn_s_setprio(0);
        }
        __syncthreads();                // stage landed (vmcnt0) + all reads done
        cur ^= 1;
    }

    // ---------------- epilogue (row-side mining; verified mapping) ---------
    float sqj[4];
    int   tj[4];
#pragma unroll
    for (int ni = 0; ni < 4; ++ni) {
        const int gj = colBase + wn * 64 + ni * 16 + lo;
        sqj[ni] = sqg[gj];
        tj[ni]  = tgt[gj];
    }
#pragma unroll
    for (int mi = 0; mi < 8; ++mi) {
#pragma unroll
        for (int j = 0; j < 4; ++j) {
            const int gi = rowBase + wm * 128 + mi * 16 + hi * 4 + j;
            const float sqi = sqg[gi];
            const int   ti  = tgt[gi];
            float ap = 0.0f;
            float an = __uint_as_float(0x7F800000u);
#pragma unroll
            for (int ni = 0; ni < 4; ++ni) {
                const float d2 = sqi + sqj[ni] - 2.0f * acc[mi][ni][j];
                const float dist = sqrtf(fmaxf(d2, EPS));
                if (ti == tj[ni]) ap = fmaxf(ap, dist);
                else              an = fminf(an, dist);
            }
            // reduce across the 16 lanes (lo) holding this row
#pragma unroll
            for (int m = 1; m < 16; m <<= 1) {
                ap = fmaxf(ap, __shfl_xor(ap, m, 64));
                an = fminf(an, __shfl_xor(an, m, 64));
            }
            if (lo == 0) {
                atomicMax(&apb[gi], __float_as_uint(ap));
                atomicMin(&anb[gi], __float_as_uint(an));
            }
        }
    }

    // ---------------- last-block finalize ----------------
    __threadfence();
    __syncthreads();
    __shared__ int lastFlag;
    if (tid == 0) {
        unsigned prev = __hip_atomic_fetch_add(ctr, 1u, __ATOMIC_ACQ_REL,
                                               __HIP_MEMORY_SCOPE_AGENT);
        lastFlag = (prev == (unsigned)(nblk - 1)) ? 1 : 0;
    }
    __syncthreads();
    if (lastFlag) {
        float ls = 0.0f, pc = 0.0f;
        for (int i = tid; i < n; i += 512) {
            const float ap = __uint_as_float(__hip_atomic_load(
                &apb[i], __ATOMIC_RELAXED, __HIP_MEMORY_SCOPE_AGENT));
            const float an = __uint_as_float(__hip_atomic_load(
                &anb[i], __ATOMIC_RELAXED, __HIP_MEMORY_SCOPE_AGENT));
            ls += fmaxf(MARGIN - (an - ap), 0.0f);
            pc += (an > ap) ? 1.0f : 0.0f;
        }
        __shared__ float rl[8], rp[8];
        for (int off = 32; off > 0; off >>= 1) {
            ls += __shfl_down(ls, off, 64);
            pc += __shfl_down(pc, off, 64);
        }
        if ((tid & 63) == 0) { rl[tid >> 6] = ls; rp[tid >> 6] = pc; }
        __syncthreads();
        if (tid == 0) {
            float L = 0.0f, P = 0.0f;
#pragma unroll
            for (int w = 0; w < 8; ++w) { L += rl[w]; P += rp[w]; }
            out[0] = L / (float)n;
            out[1] = P / (float)n;
        }
    }
}

// ---------------------------------------------------------------------------
// Fallback path (only if shape/ws unsupported): pure fp32, zero workspace.
// ---------------------------------------------------------------------------
__global__ __launch_bounds__(256) void fb_zero(float* __restrict__ out) {
    if (threadIdx.x == 0) { out[0] = 0.0f; out[1] = 0.0f; }
}

__global__ __launch_bounds__(256) void fb_row(
    const float* __restrict__ X, const int* __restrict__ tgt,
    float* __restrict__ out, int n, int d) {
    __shared__ float xi[4096];  // supports d <= 4096
    const int i = blockIdx.x;
    const int tid = threadIdx.x;
    for (int k = tid; k < d; k += 256) xi[k] = X[(size_t)i * d + k];
    __syncthreads();
    const int ti = tgt[i];
    float ap = 0.0f;
    float an = __uint_as_float(0x7F800000u);
    for (int j = tid; j < n; j += 256) {
        const float4* Xj = (const float4*)(X + (size_t)j * d);
        float s = 0.0f;
        for (int k4 = 0; k4 < (d >> 2); ++k4) {
            float4 v = Xj[k4];
            float4 u = *(const float4*)&xi[k4 * 4];
            float dx = u.x - v.x, dy = u.y - v.y, dz = u.z - v.z, dw = u.w - v.w;
            s += dx * dx + dy * dy + dz * dz + dw * dw;
        }
        const float dist = sqrtf(fmaxf(s, EPS));
        if (tgt[j] == ti) ap = fmaxf(ap, dist);
        else              an = fminf(an, dist);
    }
    for (int m = 1; m < 64; m <<= 1) {
        ap = fmaxf(ap, __shfl_xor(ap, m, 64));
        an = fminf(an, __shfl_xor(an, m, 64));
    }
    __shared__ float rap[4], ran[4];
    const int wave = tid >> 6, lane = tid & 63;
    if (lane == 0) { rap[wave] = ap; ran[wave] = an; }
    __syncthreads();
    if (tid == 0) {
        ap = fmaxf(fmaxf(rap[0], rap[1]), fmaxf(rap[2], rap[3]));
        an = fminf(fminf(ran[0], ran[1]), fminf(ran[2], ran[3]));
        atomicAdd(&out[0], fmaxf(MARGIN - (an - ap), 0.0f));
        atomicAdd(&out[1], (an > ap) ? 1.0f : 0.0f);
    }
}

__global__ __launch_bounds__(64) void fb_scale(float* __restrict__ out, float inv_n) {
    if (threadIdx.x == 0) { out[0] *= inv_n; out[1] *= inv_n; }
}

// ---------------------------------------------------------------------------
extern "C" void kernel_launch(void* const* d_in, const int* in_sizes, int n_in,
                              void* d_out, int out_size, void* d_ws, size_t ws_size,
                              hipStream_t stream) {
    const float* X   = (const float*)d_in[0];
    const int*   tgt = (const int*)d_in[1];
    const int n = in_sizes[1];
    const int d = in_sizes[0] / n;

    const size_t need = (size_t)n * d * 2 + (size_t)n * 4 * 3 + 4;
    if (ws_size >= need && (n % BM) == 0 && (d % BK) == 0 &&
        ((n / BM) % 8 == 0 || (n / BM) * (n / BM) % 8 == 0)) {
        char* ws = (char*)d_ws;
        unsigned short* Xbf = (unsigned short*)ws;                 // n*d*2 B
        float*    sqg = (float*)(ws + (size_t)n * d * 2);          // n*4 B
        unsigned* apb = (unsigned*)((char*)sqg + (size_t)n * 4);   // n*4 B
        unsigned* anb = apb + n;                                   // n*4 B
        unsigned* ctr = anb + n;                                   // 4 B

        const int nb = n / BM;                 // 16
        const int nblk = nb * nb;              // 256
        prep_kernel<<<n / 4, 256, 0, stream>>>(X, Xbf, sqg, apb, anb, ctr, d);
        gram_gemm<<<nblk, 512, 0, stream>>>(Xbf, sqg, tgt, apb, anb, ctr,
                                            (float*)d_out, n, d, nblk);
    } else {
        fb_zero<<<1, 256, 0, stream>>>((float*)d_out);
        fb_row<<<n, 256, 0, stream>>>(X, tgt, (float*)d_out, n, d);
        fb_scale<<<1, 64, 0, stream>>>((float*)d_out, 1.0f / (float)n);
    }
}

// Round 13
// 149.865 us; speedup vs baseline: 1.0645x; 1.0292x over previous
//
#include <hip/hip_runtime.h>
#include <stdint.h>

#define MARGIN 0.3f
#define EPS 1e-12f

typedef __attribute__((ext_vector_type(8))) __bf16 bf16x8;
typedef __attribute__((ext_vector_type(4))) float f32x4;

// round-to-nearest-even fp32 -> bf16
__device__ __forceinline__ unsigned short f2bf(float f) {
    unsigned u = __float_as_uint(f);
    unsigned r = (u + 0x7FFFu + ((u >> 16) & 1u)) >> 16;
    return (unsigned short)r;
}

#define GLD16(gp, lp)                                                     \
    __builtin_amdgcn_global_load_lds(                                     \
        (const __attribute__((address_space(1))) void*)(gp),              \
        (__attribute__((address_space(3))) void*)(lp), 16, 0, 0)

// ---------------------------------------------------------------------------
// Kernel 1: fp32 -> bf16 convert, fp32 row norms, init ap/an/ctr.
// ---------------------------------------------------------------------------
__global__ __launch_bounds__(256) void prep_kernel(
    const float* __restrict__ X, unsigned short* __restrict__ Xbf,
    float* __restrict__ sqg, unsigned* __restrict__ apb,
    unsigned* __restrict__ anb, unsigned* __restrict__ ctr, int d) {
    const int wave = threadIdx.x >> 6, lane = threadIdx.x & 63;
    const int row = blockIdx.x * 4 + wave;
    const float4* Xr = (const float4*)(X + (size_t)row * d);
    ushort4* Or = (ushort4*)(Xbf + (size_t)row * d);
    float s = 0.0f;
    const int nq = d >> 2;
    for (int i = lane; i < nq; i += 64) {
        float4 v = Xr[i];
        s += v.x * v.x + v.y * v.y + v.z * v.z + v.w * v.w;
        ushort4 o;
        o.x = f2bf(v.x); o.y = f2bf(v.y); o.z = f2bf(v.z); o.w = f2bf(v.w);
        Or[i] = o;
    }
    for (int off = 32; off > 0; off >>= 1) s += __shfl_down(s, off, 64);
    if (lane == 0) {
        sqg[row] = s;
        apb[row] = 0u;            // dist >= 0: uint compare == float compare
        anb[row] = 0x7F800000u;   // +inf
    }
    if (blockIdx.x == 0 && threadIdx.x == 0) ctr[0] = 0u;
}

// ---------------------------------------------------------------------------
// Kernel 2: 256x256 full-square Gram + distance + row-side hard mining.
// 4-phase counted-vmcnt pipeline (T3+T4): per K-tile T, each phase issues one
// half-tile stage (2 GLD16) for tile T+1/T+2, and ONLY P1 has a vmcnt(4)
// (proven: exactly 4 loads issue after A(T)h2, so vmcnt(4) => tile T landed).
// No vmcnt(0) drain in the loop; raw s_barriers; T2 source-swizzle (conflict
// -free, verified r11); T5 setprio around MFMA clusters.
// ---------------------------------------------------------------------------
#define BM 256
#define BN 256
#define BK 64

__global__ __launch_bounds__(512, 2) void gram_gemm(
    const unsigned short* __restrict__ Xbf, const float* __restrict__ sqg,
    const int* __restrict__ tgt, unsigned* __restrict__ apb,
    unsigned* __restrict__ anb, unsigned* __restrict__ ctr,
    float* __restrict__ out, int n, int d, int nblk) {
    __shared__ unsigned short ldsA[2][BM * BK];   // 2 x 32 KB
    __shared__ unsigned short ldsB[2][BN * BK];   // 2 x 32 KB

    const int tid  = threadIdx.x;
    const int lane = tid & 63;
    const int wave = tid >> 6;          // 0..7
    const int wm = wave >> 2;           // 0..1 (row group of 128)
    const int wn = wave & 3;            // 0..3 (col group of 64)
    const int lo = lane & 15, hi = lane >> 4;

    // XCD swizzle: 256 blocks -> xcd gets 32 consecutive bids (2 A-panels)
    const int orig = blockIdx.x;
    const int bid = (orig & 7) * 32 + (orig >> 3);
    const int bi = bid >> 4, bj = bid & 15;
    const int rowBase = bi * BM;
    const int colBase = bj * BN;

    // staging: half-tile = 128 rows of one matrix (16 KB); wave w covers rows
    // h*128 + w*16 .. +15 as 2 chunks of 8 rows (2 GLD16). Source k-slot is
    // pre-swizzled (slot ^= row&7) so the LINEAR LDS landing is bank-spread.
    const int srow = lane >> 3;                   // 0..7 within 8-row chunk
    const int sk   = (((lane & 7) ^ srow) * 8);   // swizzled k-offset (elems)
    const unsigned short* gA[2][2];
    const unsigned short* gB[2][2];
    int dA[2][2], dB[2][2];
#pragma unroll
    for (int h = 0; h < 2; ++h)
#pragma unroll
        for (int c = 0; c < 2; ++c) {
            const int rr = h * 128 + wave * 16 + c * 8;
            gA[h][c] = Xbf + (size_t)(rowBase + rr + srow) * d + sk;
            gB[h][c] = Xbf + (size_t)(colBase + rr + srow) * d + sk;
            dA[h][c] = rr * BK;
            dB[h][c] = rr * BK;
        }

#define STG_A(buf, h, k0)                                                  \
    do { GLD16(gA[h][0] + (k0), &ldsA[buf][dA[h][0]]);                     \
         GLD16(gA[h][1] + (k0), &ldsA[buf][dA[h][1]]); } while (0)
#define STG_B(buf, h, k0)                                                  \
    do { GLD16(gB[h][0] + (k0), &ldsB[buf][dB[h][0]]);                     \
         GLD16(gB[h][1] + (k0), &ldsB[buf][dB[h][1]]); } while (0)

    f32x4 acc[8][4] = {};
    const int nt = d / BK;                  // 16
    const int sl0 = (hi ^ (lo & 7)) * 8;          // kk0 read slot (swizzled)
    const int sl1 = ((4 + hi) ^ (lo & 7)) * 8;    // kk1 read slot

    // prologue (per-wave issue order matters for the vmcnt proof):
    STG_B(0, 0, 0);        // B(0)h1
    STG_B(0, 1, 0);        // B(0)h2
    STG_A(0, 0, 0);        // A(0)h1
    STG_A(0, 1, 0);        // A(0)h2
    STG_B(1, 0, BK);       // B(1)h1

    bf16x8 a[4], b0[4], b1[4];

    for (int T = 0; T < nt - 1; ++T) {
        const int cb = T & 1, nbuf = cb ^ 1;
        const int kn = (T + 1) * BK;
        // ---- P1: stage B(T+1)h2; vmcnt(4); barrier; kk0 mi0-3 + B kk0 ----
        STG_B(nbuf, 1, kn);
        asm volatile("s_waitcnt vmcnt(4)" ::: "memory");
        asm volatile("s_barrier" ::: "memory");
#pragma unroll
        for (int mi = 0; mi < 4; ++mi)
            a[mi] = *(const bf16x8*)&ldsA[cb][(wm * 128 + mi * 16 + lo) * BK + sl0];
#pragma unroll
        for (int ni = 0; ni < 4; ++ni)
            b0[ni] = *(const bf16x8*)&ldsB[cb][(wn * 64 + ni * 16 + lo) * BK + sl0];
        __builtin_amdgcn_s_setprio(1);
#pragma unroll
        for (int mi = 0; mi < 4; ++mi)
#pragma unroll
            for (int ni = 0; ni < 4; ++ni)
                acc[mi][ni] = __builtin_amdgcn_mfma_f32_16x16x32_bf16(
                    a[mi], b0[ni], acc[mi][ni], 0, 0, 0);
        __builtin_amdgcn_s_setprio(0);
        // ---- P2: stage A(T+1)h1; barrier; kk0 mi4-7 ----
        STG_A(nbuf, 0, kn);
        asm volatile("s_barrier" ::: "memory");
#pragma unroll
        for (int mi = 0; mi < 4; ++mi)
            a[mi] = *(const bf16x8*)&ldsA[cb][(wm * 128 + (mi + 4) * 16 + lo) * BK + sl0];
        __builtin_amdgcn_s_setprio(1);
#pragma unroll
        for (int mi = 0; mi < 4; ++mi)
#pragma unroll
            for (int ni = 0; ni < 4; ++ni)
                acc[mi + 4][ni] = __builtin_amdgcn_mfma_f32_16x16x32_bf16(
                    a[mi], b0[ni], acc[mi + 4][ni], 0, 0, 0);
        __builtin_amdgcn_s_setprio(0);
        // ---- P3: stage A(T+1)h2; barrier; kk1 mi0-3 + B kk1 ----
        STG_A(nbuf, 1, kn);
        asm volatile("s_barrier" ::: "memory");
#pragma unroll
        for (int mi = 0; mi < 4; ++mi)
            a[mi] = *(const bf16x8*)&ldsA[cb][(wm * 128 + mi * 16 + lo) * BK + sl1];
#pragma unroll
        for (int ni = 0; ni < 4; ++ni)
            b1[ni] = *(const bf16x8*)&ldsB[cb][(wn * 64 + ni * 16 + lo) * BK + sl1];
        __builtin_amdgcn_s_setprio(1);
#pragma unroll
        for (int mi = 0; mi < 4; ++mi)
#pragma unroll
            for (int ni = 0; ni < 4; ++ni)
                acc[mi][ni] = __builtin_amdgcn_mfma_f32_16x16x32_bf16(
                    a[mi], b1[ni], acc[mi][ni], 0, 0, 0);
        __builtin_amdgcn_s_setprio(0);
        // ---- P4: barrier FIRST (closes P3's B-kk1 reads); stage B(T+2)h1
        //      into CURRENT buffer (B fully read); kk1 mi4-7 ----
        asm volatile("s_barrier" ::: "memory");
        if (T < nt - 2) STG_B(cb, 0, kn + BK);
#pragma unroll
        for (int mi = 0; mi < 4; ++mi)
            a[mi] = *(const bf16x8*)&ldsA[cb][(wm * 128 + (mi + 4) * 16 + lo) * BK + sl1];
        __builtin_amdgcn_s_setprio(1);
#pragma unroll
        for (int mi = 0; mi < 4; ++mi)
#pragma unroll
            for (int ni = 0; ni < 4; ++ni)
                acc[mi + 4][ni] = __builtin_amdgcn_mfma_f32_16x16x32_bf16(
                    a[mi], b1[ni], acc[mi + 4][ni], 0, 0, 0);
        __builtin_amdgcn_s_setprio(0);
    }
    // ---- peeled last K-tile (T = nt-1): no stages, single drain ----
    {
        const int cb = (nt - 1) & 1;
        asm volatile("s_waitcnt vmcnt(0)" ::: "memory");
        asm volatile("s_barrier" ::: "memory");
#pragma unroll
        for (int half = 0; half < 2; ++half) {
            const int sl = half ? sl1 : sl0;
#pragma unroll
            for (int ni = 0; ni < 4; ++ni)
                b0[ni] = *(const bf16x8*)&ldsB[cb][(wn * 64 + ni * 16 + lo) * BK + sl];
#pragma unroll
            for (int mh = 0; mh < 2; ++mh) {
#pragma unroll
                for (int mi = 0; mi < 4; ++mi)
                    a[mi] = *(const bf16x8*)
                        &ldsA[cb][(wm * 128 + (mi + mh * 4) * 16 + lo) * BK + sl];
                __builtin_amdgcn_s_setprio(1);
#pragma unroll
                for (int mi = 0; mi < 4; ++mi)
#pragma unroll
                    for (int ni = 0; ni < 4; ++ni)
                        acc[mi + mh * 4][ni] = __builtin_amdgcn_mfma_f32_16x16x32_bf16(
                            a[mi], b0[ni], acc[mi + mh * 4][ni], 0, 0, 0);
                __builtin_amdgcn_s_setprio(0);
            }
        }
    }

    // ---------------- epilogue (row-side mining; verified mapping) ---------
    float sqj[4];
    int   tj[4];
#pragma unroll
    for (int ni = 0; ni < 4; ++ni) {
        const int gj = colBase + wn * 64 + ni * 16 + lo;
        sqj[ni] = sqg[gj];
        tj[ni]  = tgt[gj];
    }
#pragma unroll
    for (int mi = 0; mi < 8; ++mi) {
#pragma unroll
        for (int j = 0; j < 4; ++j) {
            const int gi = rowBase + wm * 128 + mi * 16 + hi * 4 + j;
            const float sqi = sqg[gi];
            const int   ti  = tgt[gi];
            float ap = 0.0f;
            float an = __uint_as_float(0x7F800000u);
#pragma unroll
            for (int ni = 0; ni < 4; ++ni) {
                const float d2 = sqi + sqj[ni] - 2.0f * acc[mi][ni][j];
                const float dist = sqrtf(fmaxf(d2, EPS));
                if (ti == tj[ni]) ap = fmaxf(ap, dist);
                else              an = fminf(an, dist);
            }
#pragma unroll
            for (int m = 1; m < 16; m <<= 1) {
                ap = fmaxf(ap, __shfl_xor(ap, m, 64));
                an = fminf(an, __shfl_xor(an, m, 64));
            }
            if (lo == 0) {
                atomicMax(&apb[gi], __float_as_uint(ap));
                atomicMin(&anb[gi], __float_as_uint(an));
            }
        }
    }

    // ---------------- last-block finalize ----------------
    __threadfence();
    __syncthreads();
    __shared__ int lastFlag;
    if (tid == 0) {
        unsigned prev = __hip_atomic_fetch_add(ctr, 1u, __ATOMIC_ACQ_REL,
                                               __HIP_MEMORY_SCOPE_AGENT);
        lastFlag = (prev == (unsigned)(nblk - 1)) ? 1 : 0;
    }
    __syncthreads();
    if (lastFlag) {
        float ls = 0.0f, pc = 0.0f;
        for (int i = tid; i < n; i += 512) {
            const float ap = __uint_as_float(__hip_atomic_load(
                &apb[i], __ATOMIC_RELAXED, __HIP_MEMORY_SCOPE_AGENT));
            const float an = __uint_as_float(__hip_atomic_load(
                &anb[i], __ATOMIC_RELAXED, __HIP_MEMORY_SCOPE_AGENT));
            ls += fmaxf(MARGIN - (an - ap), 0.0f);
            pc += (an > ap) ? 1.0f : 0.0f;
        }
        __shared__ float rl[8], rp[8];
        for (int off = 32; off > 0; off >>= 1) {
            ls += __shfl_down(ls, off, 64);
            pc += __shfl_down(pc, off, 64);
        }
        if ((tid & 63) == 0) { rl[tid >> 6] = ls; rp[tid >> 6] = pc; }
        __syncthreads();
        if (tid == 0) {
            float L = 0.0f, P = 0.0f;
#pragma unroll
            for (int w = 0; w < 8; ++w) { L += rl[w]; P += rp[w]; }
            out[0] = L / (float)n;
            out[1] = P / (float)n;
        }
    }
}

// ---------------------------------------------------------------------------
// Fallback path (only if shape/ws unsupported): pure fp32, zero workspace.
// ---------------------------------------------------------------------------
__global__ __launch_bounds__(256) void fb_zero(float* __restrict__ out) {
    if (threadIdx.x == 0) { out[0] = 0.0f; out[1] = 0.0f; }
}

__global__ __launch_bounds__(256) void fb_row(
    const float* __restrict__ X, const int* __restrict__ tgt,
    float* __restrict__ out, int n, int d) {
    __shared__ float xi[4096];  // supports d <= 4096
    const int i = blockIdx.x;
    const int tid = threadIdx.x;
    for (int k = tid; k < d; k += 256) xi[k] = X[(size_t)i * d + k];
    __syncthreads();
    const int ti = tgt[i];
    float ap = 0.0f;
    float an = __uint_as_float(0x7F800000u);
    for (int j = tid; j < n; j += 256) {
        const float4* Xj = (const float4*)(X + (size_t)j * d);
        float s = 0.0f;
        for (int k4 = 0; k4 < (d >> 2); ++k4) {
            float4 v = Xj[k4];
            float4 u = *(const float4*)&xi[k4 * 4];
            float dx = u.x - v.x, dy = u.y - v.y, dz = u.z - v.z, dw = u.w - v.w;
            s += dx * dx + dy * dy + dz * dz + dw * dw;
        }
        const float dist = sqrtf(fmaxf(s, EPS));
        if (tgt[j] == ti) ap = fmaxf(ap, dist);
        else              an = fminf(an, dist);
    }
    for (int m = 1; m < 64; m <<= 1) {
        ap = fmaxf(ap, __shfl_xor(ap, m, 64));
        an = fminf(an, __shfl_xor(an, m, 64));
    }
    __shared__ float rap[4], ran[4];
    const int wave = tid >> 6, lane = tid & 63;
    if (lane == 0) { rap[wave] = ap; ran[wave] = an; }
    __syncthreads();
    if (tid == 0) {
        ap = fmaxf(fmaxf(rap[0], rap[1]), fmaxf(rap[2], rap[3]));
        an = fminf(fminf(ran[0], ran[1]), fminf(ran[2], ran[3]));
        atomicAdd(&out[0], fmaxf(MARGIN - (an - ap), 0.0f));
        atomicAdd(&out[1], (an > ap) ? 1.0f : 0.0f);
    }
}

__global__ __launch_bounds__(64) void fb_scale(float* __restrict__ out, float inv_n) {
    if (threadIdx.x == 0) { out[0] *= inv_n; out[1] *= inv_n; }
}

// ---------------------------------------------------------------------------
extern "C" void kernel_launch(void* const* d_in, const int* in_sizes, int n_in,
                              void* d_out, int out_size, void* d_ws, size_t ws_size,
                              hipStream_t stream) {
    const float* X   = (const float*)d_in[0];
    const int*   tgt = (const int*)d_in[1];
    const int n = in_sizes[1];
    const int d = in_sizes[0] / n;

    const size_t need = (size_t)n * d * 2 + (size_t)n * 4 * 3 + 4;
    if (ws_size >= need && (n % BM) == 0 && (d % (2 * BK)) == 0 &&
        ((n / BM) * (n / BM)) % 8 == 0) {
        char* ws = (char*)d_ws;
        unsigned short* Xbf = (unsigned short*)ws;                 // n*d*2 B
        float*    sqg = (float*)(ws + (size_t)n * d * 2);          // n*4 B
        unsigned* apb = (unsigned*)((char*)sqg + (size_t)n * 4);   // n*4 B
        unsigned* anb = apb + n;                                   // n*4 B
        unsigned* ctr = anb + n;                                   // 4 B

        const int nb = n / BM;                 // 16
        const int nblk = nb * nb;              // 256
        prep_kernel<<<n / 4, 256, 0, stream>>>(X, Xbf, sqg, apb, anb, ctr, d);
        gram_gemm<<<nblk, 512, 0, stream>>>(Xbf, sqg, tgt, apb, anb, ctr,
                                            (float*)d_out, n, d, nblk);
    } else {
        fb_zero<<<1, 256, 0, stream>>>((float*)d_out);
        fb_row<<<n, 256, 0, stream>>>(X, tgt, (float*)d_out, n, d);
        fb_scale<<<1, 64, 0, stream>>>((float*)d_out, 1.0f / (float)n);
    }
}